// Round 4
// baseline (134.460 us; speedup 1.0000x reference)
//
#include <hip/hip_runtime.h>
#include <stdint.h>

// ---------------------------------------------------------------------------
// RBF attention, bf16 MFMA pipeline (verified 16x16x32 layouts):
//   x(f32)->bf16 ; W->W^T bf16 ; QKV gemm (Q,K head-split, V transposed) ;
//   coef-folded row norms ; fused exp(-g*s*||q-k||^2) attention with
//   32q x 64kv wave blocking, reg-staged K/V (T14 async-stage split, raw
//   barriers, no vmcnt drain in loop) ; out gemm -> f32
// ---------------------------------------------------------------------------

typedef __attribute__((ext_vector_type(4))) float f32x4;
typedef __attribute__((ext_vector_type(8))) short s16x8;
typedef __attribute__((ext_vector_type(2))) unsigned int u32x2;
typedef __attribute__((ext_vector_type(4))) unsigned int u32x4;

#define S_LEN 4096
#define NHEAD 12
#define DE 768

__device__ __forceinline__ uint16_t f2bf(float f) {
  unsigned u = __float_as_uint(f);
  u += 0x7fffu + ((u >> 16) & 1u);   // RNE
  return (uint16_t)(u >> 16);
}

__device__ __forceinline__ unsigned cvt_pk_bf16(float a, float b) {
  unsigned r;
  asm("v_cvt_pk_bf16_f32 %0, %1, %2" : "=v"(r) : "v"(a), "v"(b));
  return r;  // low16 = bf16(a), high16 = bf16(b)
}

__device__ __forceinline__ void gll16(const void* g, void* l) {
  __builtin_amdgcn_global_load_lds(
      (const __attribute__((address_space(1))) unsigned int*)g,
      (__attribute__((address_space(3))) unsigned int*)l, 16, 0, 0);
}

// ---------------- stage 0: conversions ----------------
__global__ void k_cvt_x(const float* __restrict__ x, uint16_t* __restrict__ xb) {
  int i = (blockIdx.x * 256 + threadIdx.x) * 4;
  float4 v = *(const float4*)(x + i);
  u32x2 o;
  o.x = (unsigned)f2bf(v.x) | ((unsigned)f2bf(v.y) << 16);
  o.y = (unsigned)f2bf(v.z) | ((unsigned)f2bf(v.w) << 16);
  *(u32x2*)(xb + i) = o;
}

__global__ void k_cvt_w(const float* __restrict__ W0, const float* __restrict__ W1,
                        const float* __restrict__ W2, const float* __restrict__ W3,
                        uint16_t* __restrict__ T0, uint16_t* __restrict__ T1,
                        uint16_t* __restrict__ T2, uint16_t* __restrict__ T3) {
  __shared__ float tile[64][65];
  int z = blockIdx.z;
  const float* W = z == 0 ? W0 : z == 1 ? W1 : z == 2 ? W2 : W3;
  uint16_t* T = z == 0 ? T0 : z == 1 ? T1 : z == 2 ? T2 : T3;
  int r0 = blockIdx.y * 64, c0 = blockIdx.x * 64;
  int t = threadIdx.x;
#pragma unroll
  for (int ii = 0; ii < 16; ++ii) {
    int idx = ii * 256 + t;
    int r = idx >> 6, c = idx & 63;
    tile[r][c] = W[(r0 + r) * DE + c0 + c];
  }
  __syncthreads();
#pragma unroll
  for (int ii = 0; ii < 16; ++ii) {
    int idx = ii * 256 + t;
    int r = idx >> 6, c = idx & 63;
    T[(size_t)(c0 + r) * DE + (r0 + c)] = f2bf(tile[c][r]);
  }
}

// ---------------- stage 1/4: GEMM  C[M,N] = A[M,K] * Bt[N,K]^T ----------------
template <int MODE>
__global__ __launch_bounds__(256) void k_gemm(
    const uint16_t* __restrict__ A, const uint16_t* __restrict__ B0,
    const uint16_t* __restrict__ B1, const uint16_t* __restrict__ B2,
    uint16_t* __restrict__ Oq, uint16_t* __restrict__ Ok, uint16_t* __restrict__ Ov,
    float* __restrict__ OF) {
  __shared__ __align__(16) uint16_t As[128 * 64];
  __shared__ __align__(16) uint16_t Bs[128 * 64];
  const int K = DE;
  int z = (MODE == 0) ? blockIdx.z : 0;
  const uint16_t* Bt = (MODE == 0) ? (z == 0 ? B0 : z == 1 ? B1 : B2) : B0;
  int m0 = blockIdx.x * 128, n0 = blockIdx.y * 128;
  int tid = threadIdx.x, lane = tid & 63, wid = tid >> 6;
  int G = lane >> 4, c = lane & 15;
  int wr = (wid >> 1) * 64, wc = (wid & 1) * 64;
  f32x4 acc[4][4] = {};
  const char* AsB = (const char*)As;
  const char* BsB = (const char*)Bs;
  for (int kt = 0; kt < K / 64; ++kt) {
#pragma unroll
    for (int i = 0; i < 4; ++i) {
      int L = (i * 256 + tid) * 16;
      int row = L >> 7, ch = (L >> 4) & 7;
      int gch = ch ^ (row & 7);
      gll16((const char*)A + ((size_t)(m0 + row) * K + kt * 64) * 2 + gch * 16,
            (char*)As + i * 4096 + wid * 1024);
      gll16((const char*)Bt + ((size_t)(n0 + row) * K + kt * 64) * 2 + gch * 16,
            (char*)Bs + i * 4096 + wid * 1024);
    }
    __syncthreads();
#pragma unroll
    for (int ks = 0; ks < 2; ++ks) {
      s16x8 a[4], b[4];
#pragma unroll
      for (int mi = 0; mi < 4; ++mi) {
        int row = wr + mi * 16 + c;
        a[mi] = *(const s16x8*)(AsB + row * 128 + (((G + 4 * ks) ^ (row & 7)) << 4));
      }
#pragma unroll
      for (int ni = 0; ni < 4; ++ni) {
        int row = wc + ni * 16 + c;
        b[ni] = *(const s16x8*)(BsB + row * 128 + (((G + 4 * ks) ^ (row & 7)) << 4));
      }
#pragma unroll
      for (int mi = 0; mi < 4; ++mi)
#pragma unroll
        for (int ni = 0; ni < 4; ++ni)
          acc[mi][ni] = __builtin_amdgcn_mfma_f32_16x16x32_bf16(a[mi], b[ni], acc[mi][ni], 0, 0, 0);
    }
    __syncthreads();
  }
#pragma unroll
  for (int mi = 0; mi < 4; ++mi) {
#pragma unroll
    for (int ni = 0; ni < 4; ++ni) {
      int r = m0 + wr + mi * 16 + G * 4;
      int n = n0 + wc + ni * 16 + c;
      if (MODE == 0) {
        int h = n >> 6, d = n & 63;
        if (z < 2) {
          uint16_t* O = (z == 0) ? Oq : Ok;
#pragma unroll
          for (int rr = 0; rr < 4; ++rr)
            O[((size_t)h * S_LEN + (r + rr)) * 64 + d] = f2bf(acc[mi][ni][rr]);
        } else {
          u32x2 pk;
          pk.x = (unsigned)f2bf(acc[mi][ni][0]) | ((unsigned)f2bf(acc[mi][ni][1]) << 16);
          pk.y = (unsigned)f2bf(acc[mi][ni][2]) | ((unsigned)f2bf(acc[mi][ni][3]) << 16);
          *(u32x2*)(Ov + ((size_t)(h * 64 + d)) * S_LEN + r) = pk;
        }
      } else {
#pragma unroll
        for (int rr = 0; rr < 4; ++rr) OF[(size_t)(r + rr) * DE + n] = acc[mi][ni][rr];
      }
    }
  }
}

// ---------------- stage 2: coef-folded row norms ----------------
__global__ void k_norm(const uint16_t* __restrict__ q, const uint16_t* __restrict__ k,
                       const float* __restrict__ gamma,
                       float* __restrict__ cqn, float* __restrict__ ckn) {
  int row = blockIdx.x * 256 + threadIdx.x;
  const int total = NHEAD * S_LEN;
  const uint16_t* src = (row < total) ? q : k;
  float* dst = (row < total) ? cqn : ckn;
  int r = (row < total) ? row : row - total;
  float coef = -gamma[r >> 12] * 0.18033688011112043f;  // 0.125*log2(e)
  const u32x4* p = (const u32x4*)(src + (size_t)r * 64);
  float s = 0.f;
#pragma unroll
  for (int i = 0; i < 8; ++i) {
    u32x4 v = p[i];
#pragma unroll
    for (int j = 0; j < 4; ++j) {
      unsigned w = v[j];
      float a = __uint_as_float(w << 16);
      float b = __uint_as_float(w & 0xffff0000u);
      s += a * a + b * b;
    }
  }
  dst[r] = coef * s;
}

// ---------------- stage 3: fused RBF attention (16x16x32, 32q x 64kv waves) --
// T14 pipeline: K/V/ckn prefetched to regs one tile ahead; ds_write at iter
// top; raw s_barrier + lgkmcnt only (prefetch loads stay in flight).
__global__ __launch_bounds__(256, 3) void k_attn(
    const uint16_t* __restrict__ q, const uint16_t* __restrict__ k,
    const uint16_t* __restrict__ vT, const float* __restrict__ cqn,
    const float* __restrict__ ckn, const float* __restrict__ gamma,
    uint16_t* __restrict__ att) {
  __shared__ __align__(16) uint16_t Ks[128 * 64];    // [kv][d] 128B rows, ch^=(kv&7)
  __shared__ __align__(16) uint16_t Vs[64 * 128];    // [d][kv] 256B rows, ch^=(d&15)
  __shared__ __align__(16) uint16_t Ps[4][32 * 64];  // per-wave [q32][kv64], ch^=(q&7)
  __shared__ __align__(16) float cks[128];
  int h = blockIdx.y;
  int tid = threadIdx.x, lane = tid & 63, wid = tid >> 6;
  int G = lane >> 4, c = lane & 15;
  int wq = wid & 1, wkv = wid >> 1;
  int qg0 = blockIdx.x * 64 + wq * 32 + c;  // qb=0 row; qb=1 is +16

  // Q B-frags: qf[qb][ks] = Q[qg][ks*32+8G+{0..7}]
  s16x8 qf[2][2];
  const char* qb0 = (const char*)(q + ((size_t)h * S_LEN + qg0) * 64);
#pragma unroll
  for (int ks = 0; ks < 2; ++ks) {
    qf[0][ks] = *(const s16x8*)(qb0 + ks * 64 + G * 16);
    qf[1][ks] = *(const s16x8*)(qb0 + 2048 + ks * 64 + G * 16);  // +16 rows
  }
  float ebq0 = __builtin_amdgcn_exp2f(cqn[h * S_LEN + qg0]);
  float ebq1 = __builtin_amdgcn_exp2f(cqn[h * S_LEN + qg0 + 16]);
  float m2c = gamma[h] * 0.36067376022224085f;  // +2*0.125*log2(e)

  f32x4 oacc[4][2] = {};
  char* PsB = (char*)Ps[wid];
  const char* KsB = (const char*)Ks;
  const char* VsB = (const char*)Vs;
  const char* kbase = (const char*)(k + (size_t)h * S_LEN * 64);
  const char* vbase = (const char*)(vT + (size_t)h * 64 * S_LEN);
  const float* cknh = ckn + h * S_LEN;
  int swzP = c & 7;

  // --- prefetch tile 0 into regs ---
  u32x4 kr[4], vr[4];
  f32x4 ckr;
#pragma unroll
  for (int i = 0; i < 4; ++i) {
    int L = (i * 256 + tid) * 16;
    int row = L >> 7, ch = (L >> 4) & 7;
    kr[i] = *(const u32x4*)(kbase + (size_t)row * 128 + ((ch ^ (row & 7)) << 4));
    int d = L >> 8, ch2 = (L >> 4) & 15;
    vr[i] = *(const u32x4*)(vbase + (size_t)d * 8192 + ((ch2 ^ (d & 15)) << 4));
  }
  if (tid < 32) ckr = *(const f32x4*)(cknh + tid * 4);

  for (int kt = 0; kt < S_LEN / 128; ++kt) {
    // (a) all waves done reading LDS tile kt-1
    asm volatile("s_waitcnt lgkmcnt(0)" ::: "memory");
    __builtin_amdgcn_s_barrier();
    // (c) stage tile kt regs -> LDS (compiler inserts vmcnt wait on kr/vr)
#pragma unroll
    for (int i = 0; i < 4; ++i) {
      *(u32x4*)((char*)Ks + (i * 256 + tid) * 16) = kr[i];
      *(u32x4*)((char*)Vs + (i * 256 + tid) * 16) = vr[i];
    }
    if (tid < 32) *(f32x4*)(cks + tid * 4) = ckr;
    // (d) prefetch tile kt+1
    if (kt + 1 < S_LEN / 128) {
#pragma unroll
      for (int i = 0; i < 4; ++i) {
        int L = (i * 256 + tid) * 16;
        int row = L >> 7, ch = (L >> 4) & 7;
        kr[i] = *(const u32x4*)(kbase + (size_t)(kt * 128 + 128 + row) * 128 + ((ch ^ (row & 7)) << 4));
        int d = L >> 8, ch2 = (L >> 4) & 15;
        vr[i] = *(const u32x4*)(vbase + (size_t)d * 8192 + kt * 256 + 256 + ((ch2 ^ (d & 15)) << 4));
      }
      if (tid < 32) ckr = *(const f32x4*)(cknh + kt * 128 + 128 + tid * 4);
    }
    // (e) tile kt visible to all waves; prefetch stays in flight
    asm volatile("s_waitcnt lgkmcnt(0)" ::: "memory");
    __builtin_amdgcn_s_barrier();
    __builtin_amdgcn_sched_barrier(0);

    // ST[kv 64-strip][q 32] = K . Q^T
    f32x4 sacc[4][2] = {};
    __builtin_amdgcn_s_setprio(1);
#pragma unroll
    for (int ks = 0; ks < 2; ++ks) {
#pragma unroll
      for (int fb = 0; fb < 4; ++fb) {
        int row = wkv * 64 + fb * 16 + c;
        s16x8 a = *(const s16x8*)(KsB + row * 128 + (((G + 4 * ks) ^ (row & 7)) << 4));
        sacc[fb][0] = __builtin_amdgcn_mfma_f32_16x16x32_bf16(a, qf[0][ks], sacc[fb][0], 0, 0, 0);
        sacc[fb][1] = __builtin_amdgcn_mfma_f32_16x16x32_bf16(a, qf[1][ks], sacc[fb][1], 0, 0, 0);
      }
    }
    __builtin_amdgcn_s_setprio(0);

    // transform: P~ = exp2(ckn + m2c*qk); C rows kv = fb*16 + 4G + r, col q = c
#pragma unroll
    for (int fb = 0; fb < 4; ++fb) {
      f32x4 ck = *(const f32x4*)&cks[wkv * 64 + fb * 16 + G * 4];
#pragma unroll
      for (int qb = 0; qb < 2; ++qb) {
        f32x4 sv = sacc[fb][qb];
        float p0 = __builtin_amdgcn_exp2f(ck[0] + m2c * sv[0]);
        float p1 = __builtin_amdgcn_exp2f(ck[1] + m2c * sv[1]);
        float p2 = __builtin_amdgcn_exp2f(ck[2] + m2c * sv[2]);
        float p3 = __builtin_amdgcn_exp2f(ck[3] + m2c * sv[3]);
        u32x2 pw;
        pw.x = cvt_pk_bf16(p0, p1);
        pw.y = cvt_pk_bf16(p2, p3);
        *(u32x2*)(PsB + (qb * 16 + c) * 128 + (((2 * fb + (G >> 1)) ^ swzP) << 4) + (G & 1) * 8) = pw;
      }
    }

    // PV: O^T[d][q] += V^T . P~ over this wave's 64-kv strip
    __builtin_amdgcn_s_setprio(1);
#pragma unroll
    for (int ks = 0; ks < 2; ++ks) {
      s16x8 b0 = *(const s16x8*)(PsB + c * 128 + (((G + 4 * ks) ^ swzP) << 4));
      s16x8 b1 = *(const s16x8*)(PsB + (16 + c) * 128 + (((G + 4 * ks) ^ swzP) << 4));
#pragma unroll
      for (int fd = 0; fd < 4; ++fd) {
        int d = fd * 16 + c;
        s16x8 va = *(const s16x8*)(VsB + d * 256 + (((wkv * 8 + G + 4 * ks) ^ (d & 15)) << 4));
        oacc[fd][0] = __builtin_amdgcn_mfma_f32_16x16x32_bf16(va, b0, oacc[fd][0], 0, 0, 0);
        oacc[fd][1] = __builtin_amdgcn_mfma_f32_16x16x32_bf16(va, b1, oacc[fd][1], 0, 0, 0);
      }
    }
    __builtin_amdgcn_s_setprio(0);
  }

  // cross-wkv reduction via f32 scratch in Ks, then exp2(cqn) scale, bf16 store
  __syncthreads();
  if (wkv == 1) {
    float* dst = (float*)Ks + wq * 2048;  // [64 d][32 q]
#pragma unroll
    for (int fd = 0; fd < 4; ++fd)
#pragma unroll
      for (int qb = 0; qb < 2; ++qb)
#pragma unroll
        for (int r = 0; r < 4; ++r)
          dst[(fd * 16 + G * 4 + r) * 32 + qb * 16 + c] = oacc[fd][qb][r];
  }
  __syncthreads();
  if (wkv == 0) {
    const float* srcp = (const float*)Ks + wq * 2048;
#pragma unroll
    for (int fd = 0; fd < 4; ++fd) {
#pragma unroll
      for (int qb = 0; qb < 2; ++qb) {
        float eb = qb ? ebq1 : ebq0;
        f32x4 v;
#pragma unroll
        for (int r = 0; r < 4; ++r)
          v[r] = (oacc[fd][qb][r] + srcp[(fd * 16 + G * 4 + r) * 32 + qb * 16 + c]) * eb;
        u32x2 w;
        w.x = cvt_pk_bf16(v[0], v[1]);
        w.y = cvt_pk_bf16(v[2], v[3]);
        *(u32x2*)(att + (size_t)(qg0 + qb * 16) * DE + h * 64 + fd * 16 + G * 4) = w;
      }
    }
  }
}

// ---------------------------------------------------------------------------
extern "C" void kernel_launch(void* const* d_in, const int* in_sizes, int n_in,
                              void* d_out, int out_size, void* d_ws, size_t ws_size,
                              hipStream_t stream) {
  (void)in_sizes; (void)n_in; (void)out_size; (void)ws_size;
  const float* x = (const float*)d_in[0];
  const float* Wq = (const float*)d_in[1];
  const float* Wk = (const float*)d_in[2];
  const float* Wv = (const float*)d_in[3];
  const float* Wo = (const float*)d_in[4];
  const float* gamma = (const float*)d_in[5];

  char* ws = (char*)d_ws;
  uint16_t* xb  = (uint16_t*)(ws);
  uint16_t* wqt = (uint16_t*)(ws + 6291456);
  uint16_t* wkt = (uint16_t*)(ws + 7471104);
  uint16_t* wvt = (uint16_t*)(ws + 8650752);
  uint16_t* wot = (uint16_t*)(ws + 9830400);
  uint16_t* qb  = (uint16_t*)(ws + 11010048);
  uint16_t* kb  = (uint16_t*)(ws + 17301504);
  uint16_t* vTb = (uint16_t*)(ws + 23592960);
  uint16_t* att = (uint16_t*)(ws + 29884416);
  float* cqn = (float*)(ws + 36175872);
  float* ckn = (float*)(ws + 36372480);

  k_cvt_x<<<3072, 256, 0, stream>>>(x, xb);
  k_cvt_w<<<dim3(12, 12, 4), 256, 0, stream>>>(Wq, Wk, Wv, Wo, wqt, wkt, wvt, wot);
  k_gemm<0><<<dim3(32, 6, 3), 256, 0, stream>>>(xb, wqt, wkt, wvt, qb, kb, vTb, nullptr);
  k_norm<<<384, 256, 0, stream>>>(qb, kb, gamma, cqn, ckn);
  k_attn<<<dim3(64, 12), 256, 0, stream>>>(qb, kb, vTb, cqn, ckn, gamma, att);
  k_gemm<1><<<dim3(32, 6, 1), 256, 0, stream>>>(att, wot, nullptr, nullptr,
                                                nullptr, nullptr, nullptr, (float*)d_out);
}

// Round 8
// 126.794 us; speedup vs baseline: 1.0605x; 1.0605x over previous
//
#include <hip/hip_runtime.h>
#include <stdint.h>

// ---------------------------------------------------------------------------
// RBF attention, bf16 MFMA pipeline (verified 16x16x32 layouts, round-3 base):
//   fused x->bf16 + W->W^T bf16 prep ; QKV gemm (Q,K head-split, V transposed);
//   coef-folded row norms ; fused exp(-g*s*||q-k||^2) attention with
//   32q x 64kv wave blocking + deferred exp2(cqn) scale ; out gemm -> f32
// ---------------------------------------------------------------------------

typedef __attribute__((ext_vector_type(4))) float f32x4;
typedef __attribute__((ext_vector_type(8))) short s16x8;
typedef __attribute__((ext_vector_type(2))) unsigned int u32x2;
typedef __attribute__((ext_vector_type(4))) unsigned int u32x4;

#define S_LEN 4096
#define NHEAD 12
#define DE 768

__device__ __forceinline__ uint16_t f2bf(float f) {
  unsigned u = __float_as_uint(f);
  u += 0x7fffu + ((u >> 16) & 1u);   // RNE
  return (uint16_t)(u >> 16);
}

__device__ __forceinline__ unsigned cvt_pk_bf16(float a, float b) {
  unsigned r;
  asm("v_cvt_pk_bf16_f32 %0, %1, %2" : "=v"(r) : "v"(a), "v"(b));
  return r;  // low16 = bf16(a), high16 = bf16(b)
}

__device__ __forceinline__ void gll16(const void* g, void* l) {
  __builtin_amdgcn_global_load_lds(
      (const __attribute__((address_space(1))) unsigned int*)g,
      (__attribute__((address_space(3))) unsigned int*)l, 16, 0, 0);
}

// ---------------- stage 0: fused conversions (cvt_x blocks + cvt_w blocks) --
__global__ void k_prep(const float* __restrict__ x, uint16_t* __restrict__ xb,
                       const float* __restrict__ W0, const float* __restrict__ W1,
                       const float* __restrict__ W2, const float* __restrict__ W3,
                       uint16_t* __restrict__ T0, uint16_t* __restrict__ T1,
                       uint16_t* __restrict__ T2, uint16_t* __restrict__ T3) {
  __shared__ float tile[64][65];
  int b = blockIdx.x;
  if (b < 3072) {  // x -> bf16 (verbatim k_cvt_x body)
    int i = (b * 256 + threadIdx.x) * 4;
    float4 v = *(const float4*)(x + i);
    u32x2 o;
    o.x = (unsigned)f2bf(v.x) | ((unsigned)f2bf(v.y) << 16);
    o.y = (unsigned)f2bf(v.z) | ((unsigned)f2bf(v.w) << 16);
    *(u32x2*)(xb + i) = o;
    return;
  }
  // W -> W^T bf16 (verbatim k_cvt_w body, decomposed block index)
  int idx = b - 3072;            // [0, 576)
  int z = idx / 144;
  int rem = idx - z * 144;
  int by = rem / 12;
  int bx = rem - by * 12;
  const float* W = z == 0 ? W0 : z == 1 ? W1 : z == 2 ? W2 : W3;
  uint16_t* T = z == 0 ? T0 : z == 1 ? T1 : z == 2 ? T2 : T3;
  int r0 = by * 64, c0 = bx * 64;
  int t = threadIdx.x;
#pragma unroll
  for (int ii = 0; ii < 16; ++ii) {
    int idx2 = ii * 256 + t;
    int r = idx2 >> 6, c = idx2 & 63;
    tile[r][c] = W[(r0 + r) * DE + c0 + c];
  }
  __syncthreads();
#pragma unroll
  for (int ii = 0; ii < 16; ++ii) {
    int idx2 = ii * 256 + t;
    int r = idx2 >> 6, c = idx2 & 63;
    T[(size_t)(c0 + r) * DE + (r0 + c)] = f2bf(tile[c][r]);
  }
}

// ---------------- stage 1/4: GEMM  C[M,N] = A[M,K] * Bt[N,K]^T ----------------
template <int MODE>
__global__ __launch_bounds__(256) void k_gemm(
    const uint16_t* __restrict__ A, const uint16_t* __restrict__ B0,
    const uint16_t* __restrict__ B1, const uint16_t* __restrict__ B2,
    uint16_t* __restrict__ Oq, uint16_t* __restrict__ Ok, uint16_t* __restrict__ Ov,
    float* __restrict__ OF) {
  __shared__ __align__(16) uint16_t As[128 * 64];
  __shared__ __align__(16) uint16_t Bs[128 * 64];
  const int K = DE;
  int z = (MODE == 0) ? blockIdx.z : 0;
  const uint16_t* Bt = (MODE == 0) ? (z == 0 ? B0 : z == 1 ? B1 : B2) : B0;
  int m0 = blockIdx.x * 128, n0 = blockIdx.y * 128;
  int tid = threadIdx.x, lane = tid & 63, wid = tid >> 6;
  int G = lane >> 4, c = lane & 15;
  int wr = (wid >> 1) * 64, wc = (wid & 1) * 64;
  f32x4 acc[4][4] = {};
  const char* AsB = (const char*)As;
  const char* BsB = (const char*)Bs;
  for (int kt = 0; kt < K / 64; ++kt) {
#pragma unroll
    for (int i = 0; i < 4; ++i) {
      int L = (i * 256 + tid) * 16;
      int row = L >> 7, ch = (L >> 4) & 7;
      int gch = ch ^ (row & 7);
      gll16((const char*)A + ((size_t)(m0 + row) * K + kt * 64) * 2 + gch * 16,
            (char*)As + i * 4096 + wid * 1024);
      gll16((const char*)Bt + ((size_t)(n0 + row) * K + kt * 64) * 2 + gch * 16,
            (char*)Bs + i * 4096 + wid * 1024);
    }
    __syncthreads();
#pragma unroll
    for (int ks = 0; ks < 2; ++ks) {
      s16x8 a[4], b[4];
#pragma unroll
      for (int mi = 0; mi < 4; ++mi) {
        int row = wr + mi * 16 + c;
        a[mi] = *(const s16x8*)(AsB + row * 128 + (((G + 4 * ks) ^ (row & 7)) << 4));
      }
#pragma unroll
      for (int ni = 0; ni < 4; ++ni) {
        int row = wc + ni * 16 + c;
        b[ni] = *(const s16x8*)(BsB + row * 128 + (((G + 4 * ks) ^ (row & 7)) << 4));
      }
#pragma unroll
      for (int mi = 0; mi < 4; ++mi)
#pragma unroll
        for (int ni = 0; ni < 4; ++ni)
          acc[mi][ni] = __builtin_amdgcn_mfma_f32_16x16x32_bf16(a[mi], b[ni], acc[mi][ni], 0, 0, 0);
    }
    __syncthreads();
  }
#pragma unroll
  for (int mi = 0; mi < 4; ++mi) {
#pragma unroll
    for (int ni = 0; ni < 4; ++ni) {
      int r = m0 + wr + mi * 16 + G * 4;
      int n = n0 + wc + ni * 16 + c;
      if (MODE == 0) {
        int h = n >> 6, d = n & 63;
        if (z < 2) {
          uint16_t* O = (z == 0) ? Oq : Ok;
#pragma unroll
          for (int rr = 0; rr < 4; ++rr)
            O[((size_t)h * S_LEN + (r + rr)) * 64 + d] = f2bf(acc[mi][ni][rr]);
        } else {
          u32x2 pk;
          pk.x = (unsigned)f2bf(acc[mi][ni][0]) | ((unsigned)f2bf(acc[mi][ni][1]) << 16);
          pk.y = (unsigned)f2bf(acc[mi][ni][2]) | ((unsigned)f2bf(acc[mi][ni][3]) << 16);
          *(u32x2*)(Ov + ((size_t)(h * 64 + d)) * S_LEN + r) = pk;
        }
      } else {
#pragma unroll
        for (int rr = 0; rr < 4; ++rr) OF[(size_t)(r + rr) * DE + n] = acc[mi][ni][rr];
      }
    }
  }
}

// ---------------- stage 2: coef-folded row norms ----------------
__global__ void k_norm(const uint16_t* __restrict__ q, const uint16_t* __restrict__ k,
                       const float* __restrict__ gamma,
                       float* __restrict__ cqn, float* __restrict__ ckn) {
  int row = blockIdx.x * 256 + threadIdx.x;
  const int total = NHEAD * S_LEN;
  const uint16_t* src = (row < total) ? q : k;
  float* dst = (row < total) ? cqn : ckn;
  int r = (row < total) ? row : row - total;
  float coef = -gamma[r >> 12] * 0.18033688011112043f;  // 0.125*log2(e)
  const u32x4* p = (const u32x4*)(src + (size_t)r * 64);
  float s = 0.f;
#pragma unroll
  for (int i = 0; i < 8; ++i) {
    u32x4 v = p[i];
#pragma unroll
    for (int j = 0; j < 4; ++j) {
      unsigned w = v[j];
      float a = __uint_as_float(w << 16);
      float b = __uint_as_float(w & 0xffff0000u);
      s += a * a + b * b;
    }
  }
  dst[r] = coef * s;
}

// ---------------- stage 3: fused RBF attention (16x16x32, 32q x 64kv waves) --
// Block: head h, 64 q rows. Wave (wq=wid&1, wkv=wid>>1): q in [wq*32,+32) as
// 2 frags, kv strip [wkv*64,+64) of each 128-tile. P~ = exp2(ckn + m2c*qk);
// epilogue: cross-wkv reduce, scale by exp2(cqn), store bf16.
__global__ __launch_bounds__(256, 3) void k_attn(
    const uint16_t* __restrict__ q, const uint16_t* __restrict__ k,
    const uint16_t* __restrict__ vT, const float* __restrict__ cqn,
    const float* __restrict__ ckn, const float* __restrict__ gamma,
    uint16_t* __restrict__ att) {
  __shared__ __align__(16) uint16_t Ks[128 * 64];    // [kv][d] 128B rows, ch^=(kv&7)
  __shared__ __align__(16) uint16_t Vs[64 * 128];    // [d][kv] 256B rows, ch^=(d&15)
  __shared__ __align__(16) uint16_t Ps[4][32 * 64];  // per-wave [q32][kv64], ch^=(q&7)
  __shared__ __align__(16) float cks[128];
  int h = blockIdx.y;
  int tid = threadIdx.x, lane = tid & 63, wid = tid >> 6;
  int G = lane >> 4, c = lane & 15;
  int wq = wid & 1, wkv = wid >> 1;
  int qg0 = blockIdx.x * 64 + wq * 32 + c;  // qb=0 row; qb=1 is +16

  // Q B-frags (verified 16x16x32 pattern): qf[qb][ks] = Q[qg][ks*32+8G+{0..7}]
  s16x8 qf[2][2];
  const char* qb0 = (const char*)(q + ((size_t)h * S_LEN + qg0) * 64);
#pragma unroll
  for (int ks = 0; ks < 2; ++ks) {
    qf[0][ks] = *(const s16x8*)(qb0 + ks * 64 + G * 16);
    qf[1][ks] = *(const s16x8*)(qb0 + 2048 + ks * 64 + G * 16);  // +16 rows
  }
  float ebq0 = __builtin_amdgcn_exp2f(cqn[h * S_LEN + qg0]);
  float ebq1 = __builtin_amdgcn_exp2f(cqn[h * S_LEN + qg0 + 16]);
  float m2c = gamma[h] * 0.36067376022224085f;  // +2*0.125*log2(e)

  f32x4 oacc[4][2] = {};
  char* PsB = (char*)Ps[wid];
  const char* KsB = (const char*)Ks;
  const char* VsB = (const char*)Vs;
  const char* kbase = (const char*)(k + (size_t)h * S_LEN * 64);
  const char* vbase = (const char*)(vT + (size_t)h * 64 * S_LEN);
  const float* cknh = ckn + h * S_LEN;
  int swzP = c & 7;

  for (int kt = 0; kt < S_LEN / 128; ++kt) {
#pragma unroll
    for (int i = 0; i < 4; ++i) {  // K tile: [128 kv][64 d]
      int L = (i * 256 + tid) * 16;
      int row = L >> 7, ch = (L >> 4) & 7;
      gll16(kbase + (size_t)(kt * 128 + row) * 128 + ((ch ^ (row & 7)) << 4),
            (char*)Ks + i * 4096 + wid * 1024);
    }
#pragma unroll
    for (int i = 0; i < 4; ++i) {  // V^T tile: [64 d][128 kv]
      int L = (i * 256 + tid) * 16;
      int d = L >> 8, ch = (L >> 4) & 15;
      gll16(vbase + (size_t)d * 8192 + kt * 256 + ((ch ^ (d & 15)) << 4),
            (char*)Vs + i * 4096 + wid * 1024);
    }
    if (tid < 32) gll16((const char*)(cknh + kt * 128) + tid * 16, (char*)cks);
    __syncthreads();

    // ST[kv 64-strip][q 32] = K . Q^T  (A = K rows, B = Q)
    f32x4 sacc[4][2] = {};
    __builtin_amdgcn_s_setprio(1);
#pragma unroll
    for (int ks = 0; ks < 2; ++ks) {
#pragma unroll
      for (int fb = 0; fb < 4; ++fb) {
        int row = wkv * 64 + fb * 16 + c;
        s16x8 a = *(const s16x8*)(KsB + row * 128 + (((G + 4 * ks) ^ (row & 7)) << 4));
        sacc[fb][0] = __builtin_amdgcn_mfma_f32_16x16x32_bf16(a, qf[0][ks], sacc[fb][0], 0, 0, 0);
        sacc[fb][1] = __builtin_amdgcn_mfma_f32_16x16x32_bf16(a, qf[1][ks], sacc[fb][1], 0, 0, 0);
      }
    }
    __builtin_amdgcn_s_setprio(0);

    // transform: P~ = exp2(ckn + m2c*qk); C rows kv = fb*16 + 4G + r, col q = c
#pragma unroll
    for (int fb = 0; fb < 4; ++fb) {
      f32x4 ck = *(const f32x4*)&cks[wkv * 64 + fb * 16 + G * 4];
#pragma unroll
      for (int qb = 0; qb < 2; ++qb) {
        f32x4 sv = sacc[fb][qb];
        float p0 = __builtin_amdgcn_exp2f(ck[0] + m2c * sv[0]);
        float p1 = __builtin_amdgcn_exp2f(ck[1] + m2c * sv[1]);
        float p2 = __builtin_amdgcn_exp2f(ck[2] + m2c * sv[2]);
        float p3 = __builtin_amdgcn_exp2f(ck[3] + m2c * sv[3]);
        u32x2 pw;
        pw.x = cvt_pk_bf16(p0, p1);
        pw.y = cvt_pk_bf16(p2, p3);
        // kv-local byte = 32*fb + 8*G -> chunk = 2*fb + (G>>1), half = G&1
        *(u32x2*)(PsB + (qb * 16 + c) * 128 + (((2 * fb + (G >> 1)) ^ swzP) << 4) + (G & 1) * 8) = pw;
      }
    }

    // PV: O^T[d][q] += V^T . P~ over this wave's 64-kv strip
    __builtin_amdgcn_s_setprio(1);
#pragma unroll
    for (int ks = 0; ks < 2; ++ks) {
      s16x8 b0 = *(const s16x8*)(PsB + c * 128 + (((G + 4 * ks) ^ swzP) << 4));
      s16x8 b1 = *(const s16x8*)(PsB + (16 + c) * 128 + (((G + 4 * ks) ^ swzP) << 4));
#pragma unroll
      for (int fd = 0; fd < 4; ++fd) {
        int d = fd * 16 + c;
        s16x8 va = *(const s16x8*)(VsB + d * 256 + (((wkv * 8 + G + 4 * ks) ^ (d & 15)) << 4));
        oacc[fd][0] = __builtin_amdgcn_mfma_f32_16x16x32_bf16(va, b0, oacc[fd][0], 0, 0, 0);
        oacc[fd][1] = __builtin_amdgcn_mfma_f32_16x16x32_bf16(va, b1, oacc[fd][1], 0, 0, 0);
      }
    }
    __builtin_amdgcn_s_setprio(0);
    __syncthreads();
  }

  // cross-wkv reduction via f32 scratch in Ks, then exp2(cqn) scale, bf16 store
  if (wkv == 1) {
    float* dst = (float*)Ks + wq * 2048;  // [64 d][32 q]
#pragma unroll
    for (int fd = 0; fd < 4; ++fd)
#pragma unroll
      for (int qb = 0; qb < 2; ++qb)
#pragma unroll
        for (int r = 0; r < 4; ++r)
          dst[(fd * 16 + G * 4 + r) * 32 + qb * 16 + c] = oacc[fd][qb][r];
  }
  __syncthreads();
  if (wkv == 0) {
    const float* srcp = (const float*)Ks + wq * 2048;
#pragma unroll
    for (int fd = 0; fd < 4; ++fd) {
#pragma unroll
      for (int qb = 0; qb < 2; ++qb) {
        float eb = qb ? ebq1 : ebq0;
        f32x4 v;
#pragma unroll
        for (int r = 0; r < 4; ++r)
          v[r] = (oacc[fd][qb][r] + srcp[(fd * 16 + G * 4 + r) * 32 + qb * 16 + c]) * eb;
        u32x2 w;
        w.x = cvt_pk_bf16(v[0], v[1]);
        w.y = cvt_pk_bf16(v[2], v[3]);
        *(u32x2*)(att + (size_t)(qg0 + qb * 16) * DE + h * 64 + fd * 16 + G * 4) = w;
      }
    }
  }
}

// ---------------------------------------------------------------------------
extern "C" void kernel_launch(void* const* d_in, const int* in_sizes, int n_in,
                              void* d_out, int out_size, void* d_ws, size_t ws_size,
                              hipStream_t stream) {
  (void)in_sizes; (void)n_in; (void)out_size; (void)ws_size;
  const float* x = (const float*)d_in[0];
  const float* Wq = (const float*)d_in[1];
  const float* Wk = (const float*)d_in[2];
  const float* Wv = (const float*)d_in[3];
  const float* Wo = (const float*)d_in[4];
  const float* gamma = (const float*)d_in[5];

  char* ws = (char*)d_ws;
  uint16_t* xb  = (uint16_t*)(ws);
  uint16_t* wqt = (uint16_t*)(ws + 6291456);
  uint16_t* wkt = (uint16_t*)(ws + 7471104);
  uint16_t* wvt = (uint16_t*)(ws + 8650752);
  uint16_t* wot = (uint16_t*)(ws + 9830400);
  uint16_t* qb  = (uint16_t*)(ws + 11010048);
  uint16_t* kb  = (uint16_t*)(ws + 17301504);
  uint16_t* vTb = (uint16_t*)(ws + 23592960);
  uint16_t* att = (uint16_t*)(ws + 29884416);
  float* cqn = (float*)(ws + 36175872);
  float* ckn = (float*)(ws + 36372480);

  k_prep<<<3648, 256, 0, stream>>>(x, xb, Wq, Wk, Wv, Wo, wqt, wkt, wvt, wot);
  k_gemm<0><<<dim3(32, 6, 3), 256, 0, stream>>>(xb, wqt, wkt, wvt, qb, kb, vTb, nullptr);
  k_norm<<<384, 256, 0, stream>>>(qb, kb, gamma, cqn, ckn);
  k_attn<<<dim3(64, 12), 256, 0, stream>>>(qb, kb, vTb, cqn, ckn, gamma, att);
  k_gemm<1><<<dim3(32, 6, 1), 256, 0, stream>>>(att, wot, nullptr, nullptr,
                                                nullptr, nullptr, nullptr, (float*)d_out);
}

// Round 12
// 125.191 us; speedup vs baseline: 1.0740x; 1.0128x over previous
//
#include <hip/hip_runtime.h>
#include <stdint.h>

// ---------------------------------------------------------------------------
// RBF attention, bf16 MFMA pipeline (verified 16x16x32 layouts, round-3 base):
//   fused x->bf16 + W->W^T bf16 prep ; QKV gemm (Q,K head-split, V transposed);
//   coef-folded row norms ; fused exp(-g*s*||q-k||^2) attention with
//   32q x 64kv wave blocking + deferred exp2(cqn) scale ; out gemm -> f32
//   k_attn pipelining: stage issue points moved (K after B1, V+cks after B2);
//   EXPLICIT s_waitcnt vmcnt(0) immediately before every barrier restores the
//   m97 drain-before-barrier semantics (cross-wave DMA visibility) while the
//   drain itself is covered by the preceding compute phase.
// ---------------------------------------------------------------------------

typedef __attribute__((ext_vector_type(4))) float f32x4;
typedef __attribute__((ext_vector_type(8))) short s16x8;
typedef __attribute__((ext_vector_type(2))) unsigned int u32x2;
typedef __attribute__((ext_vector_type(4))) unsigned int u32x4;

#define S_LEN 4096
#define NHEAD 12
#define DE 768

__device__ __forceinline__ uint16_t f2bf(float f) {
  unsigned u = __float_as_uint(f);
  u += 0x7fffu + ((u >> 16) & 1u);   // RNE
  return (uint16_t)(u >> 16);
}

__device__ __forceinline__ unsigned cvt_pk_bf16(float a, float b) {
  unsigned r;
  asm("v_cvt_pk_bf16_f32 %0, %1, %2" : "=v"(r) : "v"(a), "v"(b));
  return r;  // low16 = bf16(a), high16 = bf16(b)
}

__device__ __forceinline__ void gll16(const void* g, void* l) {
  __builtin_amdgcn_global_load_lds(
      (const __attribute__((address_space(1))) unsigned int*)g,
      (__attribute__((address_space(3))) unsigned int*)l, 16, 0, 0);
}

__device__ __forceinline__ void drain_vm() {
  asm volatile("s_waitcnt vmcnt(0)" ::: "memory");
}

// ---------------- stage 0: fused conversions (cvt_x blocks + cvt_w blocks) --
__global__ void k_prep(const float* __restrict__ x, uint16_t* __restrict__ xb,
                       const float* __restrict__ W0, const float* __restrict__ W1,
                       const float* __restrict__ W2, const float* __restrict__ W3,
                       uint16_t* __restrict__ T0, uint16_t* __restrict__ T1,
                       uint16_t* __restrict__ T2, uint16_t* __restrict__ T3) {
  __shared__ float tile[64][65];
  int b = blockIdx.x;
  if (b < 3072) {  // x -> bf16
    int i = (b * 256 + threadIdx.x) * 4;
    float4 v = *(const float4*)(x + i);
    u32x2 o;
    o.x = (unsigned)f2bf(v.x) | ((unsigned)f2bf(v.y) << 16);
    o.y = (unsigned)f2bf(v.z) | ((unsigned)f2bf(v.w) << 16);
    *(u32x2*)(xb + i) = o;
    return;
  }
  // W -> W^T bf16
  int idx = b - 3072;            // [0, 576)
  int z = idx / 144;
  int rem = idx - z * 144;
  int by = rem / 12;
  int bx = rem - by * 12;
  const float* W = z == 0 ? W0 : z == 1 ? W1 : z == 2 ? W2 : W3;
  uint16_t* T = z == 0 ? T0 : z == 1 ? T1 : z == 2 ? T2 : T3;
  int r0 = by * 64, c0 = bx * 64;
  int t = threadIdx.x;
#pragma unroll
  for (int ii = 0; ii < 16; ++ii) {
    int idx2 = ii * 256 + t;
    int r = idx2 >> 6, c = idx2 & 63;
    tile[r][c] = W[(r0 + r) * DE + c0 + c];
  }
  __syncthreads();
#pragma unroll
  for (int ii = 0; ii < 16; ++ii) {
    int idx2 = ii * 256 + t;
    int r = idx2 >> 6, c = idx2 & 63;
    T[(size_t)(c0 + r) * DE + (r0 + c)] = f2bf(tile[c][r]);
  }
}

// ---------------- stage 1/4: GEMM  C[M,N] = A[M,K] * Bt[N,K]^T ----------------
template <int MODE>
__global__ __launch_bounds__(256) void k_gemm(
    const uint16_t* __restrict__ A, const uint16_t* __restrict__ B0,
    const uint16_t* __restrict__ B1, const uint16_t* __restrict__ B2,
    uint16_t* __restrict__ Oq, uint16_t* __restrict__ Ok, uint16_t* __restrict__ Ov,
    float* __restrict__ OF) {
  __shared__ __align__(16) uint16_t As[128 * 64];
  __shared__ __align__(16) uint16_t Bs[128 * 64];
  const int K = DE;
  int z = (MODE == 0) ? blockIdx.z : 0;
  const uint16_t* Bt = (MODE == 0) ? (z == 0 ? B0 : z == 1 ? B1 : B2) : B0;
  int m0 = blockIdx.x * 128, n0 = blockIdx.y * 128;
  int tid = threadIdx.x, lane = tid & 63, wid = tid >> 6;
  int G = lane >> 4, c = lane & 15;
  int wr = (wid >> 1) * 64, wc = (wid & 1) * 64;
  f32x4 acc[4][4] = {};
  const char* AsB = (const char*)As;
  const char* BsB = (const char*)Bs;
  for (int kt = 0; kt < K / 64; ++kt) {
#pragma unroll
    for (int i = 0; i < 4; ++i) {
      int L = (i * 256 + tid) * 16;
      int row = L >> 7, ch = (L >> 4) & 7;
      int gch = ch ^ (row & 7);
      gll16((const char*)A + ((size_t)(m0 + row) * K + kt * 64) * 2 + gch * 16,
            (char*)As + i * 4096 + wid * 1024);
      gll16((const char*)Bt + ((size_t)(n0 + row) * K + kt * 64) * 2 + gch * 16,
            (char*)Bs + i * 4096 + wid * 1024);
    }
    __syncthreads();
#pragma unroll
    for (int ks = 0; ks < 2; ++ks) {
      s16x8 a[4], b[4];
#pragma unroll
      for (int mi = 0; mi < 4; ++mi) {
        int row = wr + mi * 16 + c;
        a[mi] = *(const s16x8*)(AsB + row * 128 + (((G + 4 * ks) ^ (row & 7)) << 4));
      }
#pragma unroll
      for (int ni = 0; ni < 4; ++ni) {
        int row = wc + ni * 16 + c;
        b[ni] = *(const s16x8*)(BsB + row * 128 + (((G + 4 * ks) ^ (row & 7)) << 4));
      }
#pragma unroll
      for (int mi = 0; mi < 4; ++mi)
#pragma unroll
        for (int ni = 0; ni < 4; ++ni)
          acc[mi][ni] = __builtin_amdgcn_mfma_f32_16x16x32_bf16(a[mi], b[ni], acc[mi][ni], 0, 0, 0);
    }
    __syncthreads();
  }
#pragma unroll
  for (int mi = 0; mi < 4; ++mi) {
#pragma unroll
    for (int ni = 0; ni < 4; ++ni) {
      int r = m0 + wr + mi * 16 + G * 4;
      int n = n0 + wc + ni * 16 + c;
      if (MODE == 0) {
        int h = n >> 6, d = n & 63;
        if (z < 2) {
          uint16_t* O = (z == 0) ? Oq : Ok;
#pragma unroll
          for (int rr = 0; rr < 4; ++rr)
            O[((size_t)h * S_LEN + (r + rr)) * 64 + d] = f2bf(acc[mi][ni][rr]);
        } else {
          u32x2 pk;
          pk.x = (unsigned)f2bf(acc[mi][ni][0]) | ((unsigned)f2bf(acc[mi][ni][1]) << 16);
          pk.y = (unsigned)f2bf(acc[mi][ni][2]) | ((unsigned)f2bf(acc[mi][ni][3]) << 16);
          *(u32x2*)(Ov + ((size_t)(h * 64 + d)) * S_LEN + r) = pk;
        }
      } else {
#pragma unroll
        for (int rr = 0; rr < 4; ++rr) OF[(size_t)(r + rr) * DE + n] = acc[mi][ni][rr];
      }
    }
  }
}

// ---------------- stage 2: coef-folded row norms ----------------
__global__ void k_norm(const uint16_t* __restrict__ q, const uint16_t* __restrict__ k,
                       const float* __restrict__ gamma,
                       float* __restrict__ cqn, float* __restrict__ ckn) {
  int row = blockIdx.x * 256 + threadIdx.x;
  const int total = NHEAD * S_LEN;
  const uint16_t* src = (row < total) ? q : k;
  float* dst = (row < total) ? cqn : ckn;
  int r = (row < total) ? row : row - total;
  float coef = -gamma[r >> 12] * 0.18033688011112043f;  // 0.125*log2(e)
  const u32x4* p = (const u32x4*)(src + (size_t)r * 64);
  float s = 0.f;
#pragma unroll
  for (int i = 0; i < 8; ++i) {
    u32x4 v = p[i];
#pragma unroll
    for (int j = 0; j < 4; ++j) {
      unsigned w = v[j];
      float a = __uint_as_float(w << 16);
      float b = __uint_as_float(w & 0xffff0000u);
      s += a * a + b * b;
    }
  }
  dst[r] = coef * s;
}

// ---------------- stage 3: fused RBF attention (16x16x32, 32q x 64kv waves) --
// B1 (post-ST, Ks free): drain_vm + barrier, then stageK(kt+1) covered by
// transform+PV. B2 (post-PV, Vs free): drain_vm + barrier, then stageV(kt+1)
// +cks covered by ST(kt+1). drain_vm-before-barrier = m97 cross-wave
// visibility; the drained DMAs were issued a full compute phase earlier.
__global__ __launch_bounds__(256, 3) void k_attn(
    const uint16_t* __restrict__ q, const uint16_t* __restrict__ k,
    const uint16_t* __restrict__ vT, const float* __restrict__ cqn,
    const float* __restrict__ ckn, const float* __restrict__ gamma,
    uint16_t* __restrict__ att) {
  __shared__ __align__(16) uint16_t Ks[128 * 64];    // [kv][d] 128B rows, ch^=(kv&7)
  __shared__ __align__(16) uint16_t Vs[64 * 128];    // [d][kv] 256B rows, ch^=(d&15)
  __shared__ __align__(16) uint16_t Ps[4][32 * 64];  // per-wave [q32][kv64], ch^=(q&7)
  __shared__ __align__(16) float cks[128];
  int h = blockIdx.y;
  int tid = threadIdx.x, lane = tid & 63, wid = tid >> 6;
  int G = lane >> 4, c = lane & 15;
  int wq = wid & 1, wkv = wid >> 1;
  int qg0 = blockIdx.x * 64 + wq * 32 + c;  // qb=0 row; qb=1 is +16

  // Q B-frags (verified 16x16x32 pattern): qf[qb][ks] = Q[qg][ks*32+8G+{0..7}]
  s16x8 qf[2][2];
  const char* qb0 = (const char*)(q + ((size_t)h * S_LEN + qg0) * 64);
#pragma unroll
  for (int ks = 0; ks < 2; ++ks) {
    qf[0][ks] = *(const s16x8*)(qb0 + ks * 64 + G * 16);
    qf[1][ks] = *(const s16x8*)(qb0 + 2048 + ks * 64 + G * 16);  // +16 rows
  }
  float ebq0 = __builtin_amdgcn_exp2f(cqn[h * S_LEN + qg0]);
  float ebq1 = __builtin_amdgcn_exp2f(cqn[h * S_LEN + qg0 + 16]);
  float m2c = gamma[h] * 0.36067376022224085f;  // +2*0.125*log2(e)

  f32x4 oacc[4][2] = {};
  char* PsB = (char*)Ps[wid];
  const char* KsB = (const char*)Ks;
  const char* VsB = (const char*)Vs;
  const char* kbase = (const char*)(k + (size_t)h * S_LEN * 64);
  const char* vbase = (const char*)(vT + (size_t)h * 64 * S_LEN);
  const float* cknh = ckn + h * S_LEN;
  int swzP = c & 7;
  const int NT = S_LEN / 128;

  auto stageK = [&](int kt) {
#pragma unroll
    for (int i = 0; i < 4; ++i) {  // K tile: [128 kv][64 d]
      int L = (i * 256 + tid) * 16;
      int row = L >> 7, ch = (L >> 4) & 7;
      gll16(kbase + (size_t)(kt * 128 + row) * 128 + ((ch ^ (row & 7)) << 4),
            (char*)Ks + i * 4096 + wid * 1024);
    }
  };
  auto stageV = [&](int kt) {
#pragma unroll
    for (int i = 0; i < 4; ++i) {  // V^T tile: [64 d][128 kv]
      int L = (i * 256 + tid) * 16;
      int d = L >> 8, ch = (L >> 4) & 15;
      gll16(vbase + (size_t)d * 8192 + kt * 256 + ((ch ^ (d & 15)) << 4),
            (char*)Vs + i * 4096 + wid * 1024);
    }
    if (tid < 32) gll16((const char*)(cknh + kt * 128) + tid * 16, (char*)cks);
  };

  // prologue: tile 0 staged, explicit drain + barrier (m97 shape)
  stageK(0);
  stageV(0);
  drain_vm();
  __syncthreads();

  for (int kt = 0; kt < NT; ++kt) {
    // ST[kv 64-strip][q 32] = K . Q^T  (A = K rows, B = Q)
    f32x4 sacc[4][2] = {};
    __builtin_amdgcn_s_setprio(1);
#pragma unroll
    for (int ks = 0; ks < 2; ++ks) {
#pragma unroll
      for (int fb = 0; fb < 4; ++fb) {
        int row = wkv * 64 + fb * 16 + c;
        s16x8 a = *(const s16x8*)(KsB + row * 128 + (((G + 4 * ks) ^ (row & 7)) << 4));
        sacc[fb][0] = __builtin_amdgcn_mfma_f32_16x16x32_bf16(a, qf[0][ks], sacc[fb][0], 0, 0, 0);
        sacc[fb][1] = __builtin_amdgcn_mfma_f32_16x16x32_bf16(a, qf[1][ks], sacc[fb][1], 0, 0, 0);
      }
    }
    __builtin_amdgcn_s_setprio(0);

    drain_vm();                      // own V(kt)+cks DMAs done (covered by ST)
    __syncthreads();                 // B1: all waves' V/cks visible; Ks free
    __builtin_amdgcn_sched_barrier(0);
    if (kt + 1 < NT) stageK(kt + 1); // covered by transform+PV below
    __builtin_amdgcn_sched_barrier(0);

    // transform: P~ = exp2(ckn + m2c*qk); C rows kv = fb*16 + 4G + r, col q = c
#pragma unroll
    for (int fb = 0; fb < 4; ++fb) {
      f32x4 ck = *(const f32x4*)&cks[wkv * 64 + fb * 16 + G * 4];
#pragma unroll
      for (int qb = 0; qb < 2; ++qb) {
        f32x4 sv = sacc[fb][qb];
        float p0 = __builtin_amdgcn_exp2f(ck[0] + m2c * sv[0]);
        float p1 = __builtin_amdgcn_exp2f(ck[1] + m2c * sv[1]);
        float p2 = __builtin_amdgcn_exp2f(ck[2] + m2c * sv[2]);
        float p3 = __builtin_amdgcn_exp2f(ck[3] + m2c * sv[3]);
        u32x2 pw;
        pw.x = cvt_pk_bf16(p0, p1);
        pw.y = cvt_pk_bf16(p2, p3);
        // kv-local byte = 32*fb + 8*G -> chunk = 2*fb + (G>>1), half = G&1
        *(u32x2*)(PsB + (qb * 16 + c) * 128 + (((2 * fb + (G >> 1)) ^ swzP) << 4) + (G & 1) * 8) = pw;
      }
    }

    // PV: O^T[d][q] += V^T . P~ over this wave's 64-kv strip
    __builtin_amdgcn_s_setprio(1);
#pragma unroll
    for (int ks = 0; ks < 2; ++ks) {
      s16x8 b0 = *(const s16x8*)(PsB + c * 128 + (((G + 4 * ks) ^ swzP) << 4));
      s16x8 b1 = *(const s16x8*)(PsB + (16 + c) * 128 + (((G + 4 * ks) ^ swzP) << 4));
#pragma unroll
      for (int fd = 0; fd < 4; ++fd) {
        int d = fd * 16 + c;
        s16x8 va = *(const s16x8*)(VsB + d * 256 + (((wkv * 8 + G + 4 * ks) ^ (d & 15)) << 4));
        oacc[fd][0] = __builtin_amdgcn_mfma_f32_16x16x32_bf16(va, b0, oacc[fd][0], 0, 0, 0);
        oacc[fd][1] = __builtin_amdgcn_mfma_f32_16x16x32_bf16(va, b1, oacc[fd][1], 0, 0, 0);
      }
    }
    __builtin_amdgcn_s_setprio(0);

    drain_vm();                      // own K(kt+1) DMAs done (covered by PV)
    __syncthreads();                 // B2: all waves' K(kt+1) visible; Vs free
    __builtin_amdgcn_sched_barrier(0);
    if (kt + 1 < NT) stageV(kt + 1); // covered by ST(kt+1)
    __builtin_amdgcn_sched_barrier(0);
  }

  // cross-wkv reduction via f32 scratch in Ks, then exp2(cqn) scale, bf16 store
  if (wkv == 1) {
    float* dst = (float*)Ks + wq * 2048;  // [64 d][32 q]
#pragma unroll
    for (int fd = 0; fd < 4; ++fd)
#pragma unroll
      for (int qb = 0; qb < 2; ++qb)
#pragma unroll
        for (int r = 0; r < 4; ++r)
          dst[(fd * 16 + G * 4 + r) * 32 + qb * 16 + c] = oacc[fd][qb][r];
  }
  __syncthreads();
  if (wkv == 0) {
    const float* srcp = (const float*)Ks + wq * 2048;
#pragma unroll
    for (int fd = 0; fd < 4; ++fd) {
#pragma unroll
      for (int qb = 0; qb < 2; ++qb) {
        float eb = qb ? ebq1 : ebq0;
        f32x4 v;
#pragma unroll
        for (int r = 0; r < 4; ++r)
          v[r] = (oacc[fd][qb][r] + srcp[(fd * 16 + G * 4 + r) * 32 + qb * 16 + c]) * eb;
        u32x2 w;
        w.x = cvt_pk_bf16(v[0], v[1]);
        w.y = cvt_pk_bf16(v[2], v[3]);
        *(u32x2*)(att + (size_t)(qg0 + qb * 16) * DE + h * 64 + fd * 16 + G * 4) = w;
      }
    }
  }
}

// ---------------------------------------------------------------------------
extern "C" void kernel_launch(void* const* d_in, const int* in_sizes, int n_in,
                              void* d_out, int out_size, void* d_ws, size_t ws_size,
                              hipStream_t stream) {
  (void)in_sizes; (void)n_in; (void)out_size; (void)ws_size;
  const float* x = (const float*)d_in[0];
  const float* Wq = (const float*)d_in[1];
  const float* Wk = (const float*)d_in[2];
  const float* Wv = (const float*)d_in[3];
  const float* Wo = (const float*)d_in[4];
  const float* gamma = (const float*)d_in[5];

  char* ws = (char*)d_ws;
  uint16_t* xb  = (uint16_t*)(ws);
  uint16_t* wqt = (uint16_t*)(ws + 6291456);
  uint16_t* wkt = (uint16_t*)(ws + 7471104);
  uint16_t* wvt = (uint16_t*)(ws + 8650752);
  uint16_t* wot = (uint16_t*)(ws + 9830400);
  uint16_t* qb  = (uint16_t*)(ws + 11010048);
  uint16_t* kb  = (uint16_t*)(ws + 17301504);
  uint16_t* vTb = (uint16_t*)(ws + 23592960);
  uint16_t* att = (uint16_t*)(ws + 29884416);
  float* cqn = (float*)(ws + 36175872);
  float* ckn = (float*)(ws + 36372480);

  k_prep<<<3648, 256, 0, stream>>>(x, xb, Wq, Wk, Wv, Wo, wqt, wkt, wvt, wot);
  k_gemm<0><<<dim3(32, 6, 3), 256, 0, stream>>>(xb, wqt, wkt, wvt, qb, kb, vTb, nullptr);
  k_norm<<<384, 256, 0, stream>>>(qb, kb, gamma, cqn, ckn);
  k_attn<<<dim3(64, 12), 256, 0, stream>>>(qb, kb, vTb, cqn, ckn, gamma, att);
  k_gemm<1><<<dim3(32, 6, 1), 256, 0, stream>>>(att, wot, nullptr, nullptr,
                                                nullptr, nullptr, nullptr, (float*)d_out);
}